// Round 1
// baseline (463.012 us; speedup 1.0000x reference)
//
#include <hip/hip_runtime.h>

// Problem constants (match reference)
#define NN    100000
#define EE    1000000
#define DD    32
#define HID   64
#define RELF  128          // 4*D
#define EPSF  1e-8f

__global__ __launch_bounds__(256)
void edge_bias_kernel(const float* __restrict__ x,
                      const int*   __restrict__ edge_index,   // [2, E] flattened
                      const float* __restrict__ W1,           // [HID, RELF]
                      const float* __restrict__ b1,           // [HID]
                      const float* __restrict__ W2,           // [1, HID]
                      const float* __restrict__ b2,           // [1]
                      float*       __restrict__ out,          // [E]
                      int E)
{
    __shared__ float sW1[HID * RELF];   // 32 KB
    __shared__ float sb1[HID];
    __shared__ float sW2[HID];

    // Stage weights into LDS (once per block; trivial vs. compute)
    for (int i = threadIdx.x; i < HID * RELF; i += blockDim.x)
        sW1[i] = W1[i];
    if (threadIdx.x < HID) {
        sb1[threadIdx.x] = b1[threadIdx.x];
        sW2[threadIdx.x] = W2[threadIdx.x];
    }
    __syncthreads();

    int e = blockIdx.x * blockDim.x + threadIdx.x;
    if (e >= E) return;

    int src = edge_index[e];        // row 0: source indices
    int dst = edge_index[E + e];    // row 1: target indices

    const float4* xi4 = (const float4*)(x + (long)src * DD);
    const float4* xj4 = (const float4*)(x + (long)dst * DD);

    // Compute relation features into registers: [ratio | log_ratio | abs_diff | rel_diff]
    float rel[RELF];
    #pragma unroll
    for (int q = 0; q < DD / 4; ++q) {
        float4 a = xi4[q];
        float4 b = xj4[q];
        float ai[4] = {a.x, a.y, a.z, a.w};
        float bj[4] = {b.x, b.y, b.z, b.w};
        #pragma unroll
        for (int t = 0; t < 4; ++t) {
            int d = q * 4 + t;
            float xi = ai[t];
            float xj = bj[t];
            float ratio = xi * __builtin_amdgcn_rcpf(xj + EPSF);
            float logr  = __logf(xi + EPSF) - __logf(xj + EPSF);
            float ad    = fabsf(xi - xj);
            float rd    = ad * __builtin_amdgcn_rcpf(fmaxf(xi, xj) + EPSF);
            rel[0 * DD + d] = ratio;
            rel[1 * DD + d] = logr;
            rel[2 * DD + d] = ad;
            rel[3 * DD + d] = rd;
        }
    }

    // MLP: out = b2 + sum_h relu(b1[h] + rel . W1[h,:]) * W2[h]
    float result = b2[0];
    for (int h = 0; h < HID; ++h) {
        const float* w = &sW1[h * RELF];
        float a0 = 0.f, a1 = 0.f, a2 = 0.f, a3 = 0.f;
        #pragma unroll
        for (int k = 0; k < RELF; k += 4) {
            a0 = fmaf(rel[k + 0], w[k + 0], a0);
            a1 = fmaf(rel[k + 1], w[k + 1], a1);
            a2 = fmaf(rel[k + 2], w[k + 2], a2);
            a3 = fmaf(rel[k + 3], w[k + 3], a3);
        }
        float acc = ((a0 + a1) + (a2 + a3)) + sb1[h];
        result = fmaf(fmaxf(acc, 0.f), sW2[h], result);
    }
    out[e] = result;
}

extern "C" void kernel_launch(void* const* d_in, const int* in_sizes, int n_in,
                              void* d_out, int out_size, void* d_ws, size_t ws_size,
                              hipStream_t stream)
{
    const float* x   = (const float*)d_in[0];
    const int*   ei  = (const int*)  d_in[1];
    const float* W1  = (const float*)d_in[2];
    const float* b1  = (const float*)d_in[3];
    const float* W2  = (const float*)d_in[4];
    const float* b2  = (const float*)d_in[5];
    float* out = (float*)d_out;

    int E = out_size;  // 1,000,000
    int block = 256;
    int grid = (E + block - 1) / block;
    edge_bias_kernel<<<grid, block, 0, stream>>>(x, ei, W1, b1, W2, b2, out, E);
}